// Round 16
// baseline (188.242 us; speedup 1.0000x reference)
//
#include <hip/hip_runtime.h>
#include <math.h>

#define ROWS   16384L
#define LSEQ   1024
#define NB     16
#define DM     256
#define DPROJ  1288
#define ZXW    1280          // zxb leading dim (dt cols dropped)
#define XBCW   768
#define DIN    512
#define DSTATE 128
#define NH     8
#define HD     64
#define QLEN   256
#define NCHUNK 4
#define NCLS   17

typedef __attribute__((ext_vector_type(8))) short s16x8;
typedef __attribute__((ext_vector_type(8))) unsigned short u16x8;
typedef __attribute__((ext_vector_type(4))) float f32x4;

#define GLOAD_LDS16(gsrc, ldst) \
  __builtin_amdgcn_global_load_lds((const __attribute__((address_space(1))) void*)(gsrc), \
      (__attribute__((address_space(3))) void*)(ldst), 16, 0, 0)

// ---- workspace map (float slots) ----
constexpr long O_GBF  = 0;
constexpr long O_ZX   = O_GBF + ROWS*DM;          // zxb bf16 [ROWS][1280]
constexpr long O_XBC  = O_ZX  + ROWS*DPROJ;
constexpr long O_DT   = O_XBC + ROWS*XBCW;
constexpr long O_ACS  = O_DT  + ROWS*NH;
constexpr long O_Y    = O_ACS + 131072;
constexpr long O_ST   = O_Y   + ROWS*DIN;         // st bf16 [512][64p][128n] (raw chunk states)
constexpr long O_Y2   = O_ST  + 4194304;
constexpr long O_XBF  = O_XBC;
constexpr long O_BBF  = O_XBC + 4200000;
constexpr long O_CBF  = O_XBC + 5300000;
constexpr long O_BT   = O_XBC + 6400000;
constexpr long O_YBF  = O_Y;
constexpr long O_XPBF = O_Y + 4300000;
constexpr long O_WCT  = O_Y + 6200000;
constexpr long O_WOUTT= O_Y + 6400000;
constexpr long O_WDT  = O_Y + 6500000;
constexpr long O_WCLST= O_Y + 6530000;
constexpr long O_WINT = O_Y + 6600000;
constexpr long O_WIPE = O_Y + 6800000;

__device__ inline unsigned short f2bf(float f) {
  union { float f; unsigned u; } v; v.f = f;
  unsigned r = v.u + 0x7FFFu + ((v.u >> 16) & 1u);
  return (unsigned short)(r >> 16);
}
__device__ inline float bf2f(unsigned short s) {
  union { unsigned u; float f; } v; v.u = ((unsigned)s) << 16; return v.f;
}

// bijective XCD-chunked swizzle (m204)
__device__ inline void xcd_swizzle(int gx, int& bx, int& by) {
  int nwg = gx * (int)gridDim.y;
  int lid = (int)blockIdx.y * gx + (int)blockIdx.x;
  int q = nwg >> 3, r = nwg & 7;
  int xcd = lid & 7, idx = lid >> 3;
  int base = xcd < r ? xcd * (q + 1) : r * (q + 1) + (xcd - r) * q;
  int w = base + idx;
  bx = w % gx; by = w / gx;
}

// ---------------- merged prep: block-range dispatch over 6 roles ----------------
__global__ __launch_bounds__(256) void prep_misc(
    const float* __restrict__ x, unsigned short* __restrict__ xp,
    const float* __restrict__ w_in, unsigned short* __restrict__ w_inT,
    const float* __restrict__ wout, unsigned short* __restrict__ woutT,
    const float* __restrict__ w_inp, const float* __restrict__ b_inp,
    unsigned short* __restrict__ we,
    float* __restrict__ Wdt, float* __restrict__ bdt,
    const float* __restrict__ wcls, float* __restrict__ wclsT)
{
  int bid = blockIdx.x;
  int tid = threadIdx.x;
  if (bid < 3584) {                                      // cast_pad_x (col 200 = 1.0)
    long idx = (long)bid * 256 + tid;
    int q = (int)(idx % 56);
    long row = idx / 56;
    ushort4 o = {0, 0, 0, 0};
    if (q < 50) {
      float4 v = *(const float4*)&x[row * 200 + q * 4];
      o.x = f2bf(v.x); o.y = f2bf(v.y); o.z = f2bf(v.z); o.w = f2bf(v.w);
    } else if (q == 50) {
      o.x = 0x3F80;
    }
    *(ushort4*)&xp[row * 224 + q * 4] = o;
  } else if (bid < 4872) {                               // tcast w_in -> w_inT [n][256]
    long i = (long)(bid - 3584) * 256 + tid;
    int k = (int)(i & 255);
    long n = i >> 8;
    w_inT[i] = f2bf(w_in[(long)k * DPROJ + n]);
  } else if (bid < 5384) {                               // tcast wout -> woutT [n][512]
    long i = (long)(bid - 4872) * 256 + tid;
    int k = (int)(i & 511);
    long n = i >> 9;
    woutT[i] = f2bf(wout[(long)k * DM + n]);
  } else if (bid < 5608) {                               // cast_winp_ext [224][256]
    int i = (bid - 5384) * 256 + tid;
    int k = i >> 8, j = i & 255;
    float v = 0.f;
    if (k < 200)       v = w_inp[(long)k * 256 + j];
    else if (k == 200) v = b_inp[j];
    we[i] = f2bf(v);
  } else if (bid < 5659) {                               // wdt_small (exact f32 dt weights)
    int k = (bid - 5608) * 4 + (tid >> 6);
    if (k > 200) return;
    int lane = tid & 63;
    int j0 = lane * 4;
    float4 xv = (k < 200) ? *(const float4*)&w_inp[(long)k * 256 + j0]
                          : *(const float4*)&b_inp[j0];
    float a0 = 0.f, a1 = 0.f, a2 = 0.f, a3 = 0.f, a4 = 0.f, a5 = 0.f, a6 = 0.f, a7 = 0.f;
    float xd[4] = {xv.x, xv.y, xv.z, xv.w};
#pragma unroll
    for (int d = 0; d < 4; ++d) {
      const float* wr = &w_in[(long)(j0 + d) * DPROJ + 1280];
      float4 wa = *(const float4*)wr;
      float4 wb = *(const float4*)(wr + 4);
      a0 = fmaf(xd[d], wa.x, a0); a1 = fmaf(xd[d], wa.y, a1);
      a2 = fmaf(xd[d], wa.z, a2); a3 = fmaf(xd[d], wa.w, a3);
      a4 = fmaf(xd[d], wb.x, a4); a5 = fmaf(xd[d], wb.y, a5);
      a6 = fmaf(xd[d], wb.z, a6); a7 = fmaf(xd[d], wb.w, a7);
    }
#pragma unroll
    for (int off = 32; off; off >>= 1) {
      a0 += __shfl_xor(a0, off); a1 += __shfl_xor(a1, off);
      a2 += __shfl_xor(a2, off); a3 += __shfl_xor(a3, off);
      a4 += __shfl_xor(a4, off); a5 += __shfl_xor(a5, off);
      a6 += __shfl_xor(a6, off); a7 += __shfl_xor(a7, off);
    }
    float o = a0;
    if (lane == 1) o = a1; if (lane == 2) o = a2; if (lane == 3) o = a3;
    if (lane == 4) o = a4; if (lane == 5) o = a5; if (lane == 6) o = a6;
    if (lane == 7) o = a7;
    if (lane < 8) {
      if (k < 200) Wdt[k * 8 + lane] = o;
      else         bdt[lane] = o;
    }
  } else {                                               // tpose_wcls
    int i = (bid - 5659) * 256 + tid;
    if (i < NCLS * 256) {
      int j = i >> 8, k = i & 255;
      wclsT[i] = wcls[(long)k * NCLS + j];
    }
  }
}

// ---------------- bf16 MFMA GEMM (global_load_lds staging + XCD swizzle) -------------
__global__ __launch_bounds__(256) void gemm_bf16(
    const unsigned short* __restrict__ A, const unsigned short* __restrict__ BT,
    float* __restrict__ C, unsigned short* __restrict__ Cb,
    const float* __restrict__ bias, int M, int N, int K)
{
  int bx, by;
  xcd_swizzle(gridDim.x, bx, by);
  __shared__ __align__(16) unsigned short As[128 * 32];
  __shared__ __align__(16) unsigned short Bs[128 * 32];
  const int tid = threadIdx.x;
  const int m0 = by * 128, n0 = bx * 128;
  const int lane = tid & 63, wv = tid >> 6;
  const int wr = (wv >> 1) * 64, wc = (wv & 1) * 64;
  f32x4 acc[4][4];
#pragma unroll
  for (int i = 0; i < 4; ++i)
#pragma unroll
    for (int j = 0; j < 4; ++j) acc[i][j] = (f32x4){0.f, 0.f, 0.f, 0.f};

  for (int k0 = 0; k0 < K; k0 += 32) {
    __syncthreads();
#pragma unroll
    for (int s = 0; s < 2; ++s) {
      int idx = (tid + 256 * s) * 8;
      int r = idx >> 5, kk = idx & 31;
      GLOAD_LDS16(&A[(long)(m0 + r) * K + k0 + kk], &As[idx]);
    }
#pragma unroll
    for (int s = 0; s < 2; ++s) {
      int idx = (tid + 256 * s) * 8;
      int n = idx >> 5, kk = idx & 31;
      int srcn = (n0 + n < N) ? (n0 + n) : 0;
      GLOAD_LDS16(&BT[(long)srcn * K + k0 + kk], &Bs[idx]);
    }
    __syncthreads();
    s16x8 af[4], bf[4];
#pragma unroll
    for (int i = 0; i < 4; ++i)
      af[i] = *(const s16x8*)&As[(wr + i * 16 + (lane & 15)) * 32 + (lane >> 4) * 8];
#pragma unroll
    for (int j = 0; j < 4; ++j)
      bf[j] = *(const s16x8*)&Bs[(wc + j * 16 + (lane & 15)) * 32 + (lane >> 4) * 8];
    __builtin_amdgcn_s_setprio(1);
#pragma unroll
    for (int i = 0; i < 4; ++i)
#pragma unroll
      for (int j = 0; j < 4; ++j)
        acc[i][j] = __builtin_amdgcn_mfma_f32_16x16x32_bf16(af[i], bf[j], acc[i][j], 0, 0, 0);
    __builtin_amdgcn_s_setprio(0);
  }
  const int cr = (lane >> 4) * 4, cc = lane & 15;
#pragma unroll
  for (int i = 0; i < 4; ++i)
#pragma unroll
    for (int j = 0; j < 4; ++j) {
      int col = n0 + wc + j * 16 + cc;
      if (col < N) {
        long rowb = (long)(m0 + wr + i * 16 + cr);
        float bv = bias ? bias[col] : 0.f;
#pragma unroll
        for (int r = 0; r < 4; ++r) {
          float v = acc[i][j][r] + bv;
          if (C)  C[(rowb + r) * N + col] = v;
          if (Cb) Cb[(rowb + r) * (long)N + col] = f2bf(v);
        }
      }
    }
}

// ---------------- merged transB + G-GEMM (block-range dispatch) ----------------
__global__ __launch_bounds__(256) void trans_g(
    const unsigned short* __restrict__ Bbf, unsigned short* __restrict__ BbfT,
    const unsigned short* __restrict__ Cbf, unsigned short* __restrict__ Gbf)
{
  const int bid = blockIdx.x;
  const int tid = threadIdx.x;
  if (bid < 128) {                                   // ---- transB ----
    __shared__ unsigned short T[128][130];
    int bc = bid >> 1, kh = bid & 1;
    long rowbase = (long)(bc >> 2) * LSEQ + (bc & 3) * QLEN + kh * 128;
    for (int e = tid; e < 128 * 128; e += 256) {
      int r = e >> 7, n = e & 127;
      T[r][n] = Bbf[(rowbase + r) * 128 + n];
    }
    __syncthreads();
    for (int e = tid; e < 128 * 128; e += 256) {
      int n = e >> 7, k = e & 127;
      BbfT[((long)bc * 128 + n) * 256 + kh * 128 + k] = T[k][n];
    }
    return;
  }
  if (bid >= 320) {                                  // ---- zero upper tile (m0=0,n0=128) ----
    int bc = bid - 320;
    unsigned short* Gout = Gbf + (long)bc * 65536;
    s16x8 z = {};
    for (int e = tid; e < 128 * 16; e += 256) {
      int r = e >> 4, seg = e & 15;
      *(s16x8*)&Gout[(long)r * 256 + 128 + seg * 8] = z;
    }
    return;
  }
  int bid2 = bid - 128;
  int t = bid2 % 3, bc = bid2 / 3;
  int m0 = (t == 0) ? 0 : 128;
  int n0 = (t == 2) ? 128 : 0;
  unsigned short* Gout = Gbf + (long)bc * 65536;
  long rowbase = (long)(bc >> 2) * LSEQ + (bc & 3) * QLEN;
  const unsigned short* A  = Cbf + rowbase * 128;
  const unsigned short* BT = Bbf + rowbase * 128;
  __shared__ __align__(16) unsigned short As[128 * 32];
  __shared__ __align__(16) unsigned short Bs[128 * 32];
  const int lane = tid & 63, wv = tid >> 6;
  const int wr = (wv >> 1) * 64, wc = (wv & 1) * 64;
  f32x4 acc[4][4];
#pragma unroll
  for (int i = 0; i < 4; ++i)
#pragma unroll
    for (int j = 0; j < 4; ++j) acc[i][j] = (f32x4){0.f, 0.f, 0.f, 0.f};
  for (int k0 = 0; k0 < 128; k0 += 32) {
    __syncthreads();
#pragma unroll
    for (int s = 0; s < 2; ++s) {
      int idx = (tid + 256 * s) * 8;
      int r = idx >> 5, kk = idx & 31;
      GLOAD_LDS16(&A[(long)(m0 + r) * 128 + k0 + kk], &As[idx]);
      GLOAD_LDS16(&BT[(long)(n0 + r) * 128 + k0 + kk], &Bs[idx]);
    }
    __syncthreads();
    s16x8 af[4], bf[4];
#pragma unroll
    for (int i = 0; i < 4; ++i)
      af[i] = *(const s16x8*)&As[(wr + i * 16 + (lane & 15)) * 32 + (lane >> 4) * 8];
#pragma unroll
    for (int j = 0; j < 4; ++j)
      bf[j] = *(const s16x8*)&Bs[(wc + j * 16 + (lane & 15)) * 32 + (lane >> 4) * 8];
    __builtin_amdgcn_s_setprio(1);
#pragma unroll
    for (int i = 0; i < 4; ++i)
#pragma unroll
      for (int j = 0; j < 4; ++j)
        acc[i][j] = __builtin_amdgcn_mfma_f32_16x16x32_bf16(af[i], bf[j], acc[i][j], 0, 0, 0);
    __builtin_amdgcn_s_setprio(0);
  }
  const int cr = (lane >> 4) * 4, cc = lane & 15;
#pragma unroll
  for (int i = 0; i < 4; ++i)
#pragma unroll
    for (int j = 0; j < 4; ++j) {
      int col = n0 + wc + j * 16 + cc;
      int qb = m0 + wr + i * 16 + cr;
#pragma unroll
      for (int r = 0; r < 4; ++r)
        Gout[(long)(qb + r) * 256 + col] = (col <= qb + r) ? f2bf(acc[i][j][r]) : (unsigned short)0;
    }
}

// ---------------- conv1d (k=4, causal) + SiLU: 4-timestep x 8-channel tiles ----------
__global__ __launch_bounds__(256) void conv_silu5(
    const unsigned short* __restrict__ zxb, const float* __restrict__ cw,
    const float* __restrict__ cb,
    unsigned short* __restrict__ Xbf, unsigned short* __restrict__ Bbf,
    unsigned short* __restrict__ Cbf)
{
  long idx = (long)blockIdx.x * 256 + threadIdx.x;
  if (idx >= (ROWS / 4) * 96) return;
  int co = (int)(idx % 96);
  long tmp = idx / 96;
  int tq = (int)(tmp & 255);
  int b = (int)(tmp >> 8);
  int ch = co * 8;
  long row0 = (long)b * LSEQ + tq * 4;
  u16x8 zv[7];
#pragma unroll
  for (int j = 0; j < 7; ++j) {
    if (j >= 3 || tq > 0)
      zv[j] = *(const u16x8*)&zxb[(row0 + j - 3) * ZXW + 512 + ch];
    else
      zv[j] = (u16x8){0, 0, 0, 0, 0, 0, 0, 0};
  }
  float cwv[4][8], cbv[8];
  {
    float4 b0 = *(const float4*)&cb[ch];
    float4 b1 = *(const float4*)&cb[ch + 4];
    cbv[0] = b0.x; cbv[1] = b0.y; cbv[2] = b0.z; cbv[3] = b0.w;
    cbv[4] = b1.x; cbv[5] = b1.y; cbv[6] = b1.z; cbv[7] = b1.w;
  }
#pragma unroll
  for (int w = 0; w < 4; ++w) {
    float4 c0 = *(const float4*)&cw[w * XBCW + ch];
    float4 c1 = *(const float4*)&cw[w * XBCW + ch + 4];
    cwv[w][0] = c0.x; cwv[w][1] = c0.y; cwv[w][2] = c0.z; cwv[w][3] = c0.w;
    cwv[w][4] = c1.x; cwv[w][5] = c1.y; cwv[w][6] = c1.z; cwv[w][7] = c1.w;
  }
#pragma unroll
  for (int i = 0; i < 4; ++i) {
    float a[8];
#pragma unroll
    for (int k = 0; k < 8; ++k) a[k] = cbv[k];
#pragma unroll
    for (int w = 0; w < 4; ++w) {
#pragma unroll
      for (int k = 0; k < 8; ++k)
        a[k] = fmaf(bf2f(zv[i + w][k]), cwv[w][k], a[k]);
    }
    u16x8 o;
#pragma unroll
    for (int k = 0; k < 8; ++k)
      o[k] = f2bf(a[k] / (1.f + __expf(-a[k])));
    long row = row0 + i;
    if (ch < 512)      *(u16x8*)&Xbf[row * DIN + ch] = o;
    else if (ch < 640) *(u16x8*)&Bbf[row * 128 + ch - 512] = o;
    else               *(u16x8*)&Cbf[row * 128 + ch - 640] = o;
  }
}

// ---------------- dt logits: block = 32 rows, LDS-staged x and Wdt; f32-exact --------
__global__ __launch_bounds__(256) void dt_logits(
    const float* __restrict__ x, const float* __restrict__ Wdt,
    const float* __restrict__ bdt, const float* __restrict__ dtb,
    float* __restrict__ dtsp)
{
  __shared__ float xs[32][201];
  __shared__ float wdt_s[1600];
  long row0 = (long)blockIdx.x * 32;
  int tid = threadIdx.x;
#pragma unroll
  for (int s = 0; s < 25; ++s) {
    int e = tid + s * 256;
    int r = e / 200, c = e % 200;
    xs[r][c] = x[(row0 + r) * 200 + c];
  }
#pragma unroll
  for (int s = 0; s < 7; ++s) {
    int e = tid + s * 256;
    if (e < 1600) wdt_s[e] = Wdt[e];
  }
  __syncthreads();
  int r = tid >> 3, h = tid & 7;
  float acc = dtb[h] + bdt[h];
  for (int i = 0; i < 200; ++i)
    acc = fmaf(xs[r][i], wdt_s[i * 8 + h], acc);
  float sp = (acc > 20.f) ? acc : log1pf(__expf(acc));
  dtsp[(row0 + r) * NH + h] = sp;
}

// ---------------- cumsum only: wave per (b,h,c) ----------------
__global__ __launch_bounds__(256) void dt_cumsum4(
    const float* __restrict__ dtsp, const float* __restrict__ alog,
    float* __restrict__ acs)
{
  int g = ((int)blockIdx.x * 256 + (int)threadIdx.x) >> 6;
  int lane = threadIdx.x & 63;
  int c = g & 3, h = (g >> 2) & 7, b = g >> 5;
  float Ah = -__expf(alog[h]);
  long rowbase = (long)b * LSEQ + c * QLEN;
  long abase = (((long)b * NH + h) * NCHUNK + c) * QLEN;
  float v[4];
#pragma unroll
  for (int j = 0; j < 4; ++j)
    v[j] = dtsp[(rowbase + lane * 4 + j) * NH + h] * Ah;
  v[1] += v[0]; v[2] += v[1]; v[3] += v[2];
  float tot = v[3];
  float run = tot;
#pragma unroll
  for (int d = 1; d < 64; d <<= 1) {
    float t = __shfl_up(run, d);
    if (lane >= d) run += t;
  }
  float excl = run - tot;
#pragma unroll
  for (int j = 0; j < 4; ++j) acs[abase + lane * 4 + j] = excl + v[j];
}

// ---------------- yd+states: balanced q-block split {0,3}/{1,2}; bf16 st -------------
__global__ __launch_bounds__(256) void yd_states7(
    const unsigned short* __restrict__ Xbf, const float* __restrict__ dtsp,
    const float* __restrict__ acs, const unsigned short* __restrict__ Gbf,
    const unsigned short* __restrict__ BbfT,
    unsigned short* __restrict__ ybf, unsigned short* __restrict__ st)
{
  int bid = blockIdx.x;
  int xcd = bid & 7, i0 = bid >> 3;
  int bc = xcd * 8 + (i0 >> 4);
  int rem = i0 & 15, h = rem >> 1, half = rem & 1;
  int c = bc & 3, b = bc >> 2;
  int bch = bc * 8 + h;

  __shared__ __align__(16) unsigned short XdT[64][264];
  __shared__ float AcsS[256], E1f[256], E2f[256], dts[256];

  const int tid = threadIdx.x;
  const int lane = tid & 63, wv = tid >> 6;
  const bool ydw = wv < 2;
  const int qb = half == 0 ? (wv == 0 ? 0 : 3) : (wv == 0 ? 1 : 2);
  const int q0 = qb * 64;
  const int n0w = half * 64 + (wv - 2) * 32;
  long rowbase = (long)b * LSEQ + c * QLEN;
  const unsigned short* Gb  = Gbf + (long)bc * 65536;
  const unsigned short* BTg = BbfT + (long)bc * 32768;

  AcsS[tid] = acs[(((long)b * NH + h) * NCHUNK + c) * QLEN + tid];
  dts[tid]  = dtsp[(rowbase + tid) * NH + h];
  __syncthreads();
  E1f[tid] = __expf(AcsS[tid] - AcsS[tid | 63]);
  E2f[tid] = __expf(AcsS[tid | 63] - AcsS[tid]);
  float rs_[4];
  rs_[0] = 1.f;
#pragma unroll
  for (int kt = 1; kt < 4; ++kt) rs_[kt] = __expf(AcsS[kt * 64 + 63] - AcsS[kt * 64 - 1]);
  __syncthreads();
  {
    int kb = wv * 64;
#pragma unroll
    for (int s = 0; s < 16; ++s) {
      int k4 = kb + s * 4;
      ushort4 pk;
      unsigned short* pp = (unsigned short*)&pk;
#pragma unroll
      for (int j = 0; j < 4; ++j) {
        int k = k4 + j;
        float v = bf2f(Xbf[(rowbase + k) * DIN + h * HD + lane]) * dts[k] * E2f[k];
        pp[j] = f2bf(v);
      }
      *(ushort4*)&XdT[lane][k4] = pk;
    }
  }
  __syncthreads();

  f32x4 accY[4][4], accS[4][2];
#pragma unroll
  for (int i = 0; i < 4; ++i)
#pragma unroll
    for (int j = 0; j < 4; ++j) accY[i][j] = (f32x4){0.f, 0.f, 0.f, 0.f};
#pragma unroll
  for (int i = 0; i < 4; ++i)
#pragma unroll
    for (int j = 0; j < 2; ++j) accS[i][j] = (f32x4){0.f, 0.f, 0.f, 0.f};

  for (int kt = 0; kt < 4; ++kt) {
    int qlo = kt * 64;
    if (ydw) {
      if (qb >= kt) {
        if (kt)
#pragma unroll
          for (int i = 0; i < 4; ++i)
#pragma unroll
            for (int j = 0; j < 4; ++j) accY[i][j] *= rs_[kt];
#pragma unroll
        for (int ks = 0; ks < 2; ++ks) {
          s16x8 bfr[4];
#pragma unroll
          for (int j = 0; j < 4; ++j)
            bfr[j] = *(const s16x8*)&XdT[j * 16 + (lane & 15)][qlo + ks * 32 + (lane >> 4) * 8];
          __builtin_amdgcn_s_setprio(1);
#pragma unroll
          for (int i = 0; i < 4; ++i) {
            s16x8 a = *(const s16x8*)&Gb[(long)(q0 + i * 16 + (lane & 15)) * 256 + qlo + ks * 32 + (lane >> 4) * 8];
#pragma unroll
            for (int j = 0; j < 4; ++j)
              accY[i][j] = __builtin_amdgcn_mfma_f32_16x16x32_bf16(a, bfr[j], accY[i][j], 0, 0, 0);
          }
          __builtin_amdgcn_s_setprio(0);
        }
      }
    } else {
      if (kt)
#pragma unroll
        for (int i = 0; i < 4; ++i)
#pragma unroll
          for (int j = 0; j < 2; ++j) accS[i][j] *= rs_[kt];
#pragma unroll
      for (int ks = 0; ks < 2; ++ks) {
        s16x8 afx[4];
#pragma unroll
        for (int i = 0; i < 4; ++i)
          afx[i] = *(const s16x8*)&XdT[i * 16 + (lane & 15)][qlo + ks * 32 + (lane >> 4) * 8];
        __builtin_amdgcn_s_setprio(1);
#pragma unroll
        for (int j2 = 0; j2 < 2; ++j2) {
          s16x8 bt = *(const s16x8*)&BTg[(long)(n0w + j2 * 16 + (lane & 15)) * 256 + qlo + ks * 32 + (lane >> 4) * 8];
#pragma unroll
          for (int i = 0; i < 4; ++i)
            accS[i][j2] = __builtin_amdgcn_mfma_f32_16x16x32_bf16(afx[i], bt, accS[i][j2], 0, 0, 0);
        }
        __builtin_amdgcn_s_setprio(0);
      }
    }
  }
  const int cr = (lane >> 4) * 4, cc = lane & 15;
  if (ydw) {
#pragma unroll
    for (int i = 0; i < 4; ++i)
#pragma unroll
      for (int j = 0; j < 4; ++j) {
        int q = q0 + i * 16 + cr;
        int p = j * 16 + cc;
#pragma unroll
        for (int r = 0; r < 4; ++r)
          ybf[(rowbase + q + r) * DIN + h * HD + p] = f2bf(accY[i][j][r] * E1f[q + r]);
      }
  } else {
#pragma unroll
    for (int i = 0; i < 4; ++i)
#pragma unroll
      for (int j2 = 0; j2 < 2; ++j2) {
        int p = i * 16 + cr;
        int n = n0w + j2 * 16 + cc;
#pragma unroll
        for (int r = 0; r < 4; ++r)
          st[(long)bch * 8192 + (long)(p + r) * 128 + n] = f2bf(accS[i][j2][r]);
      }
  }
}

// ---------------- Yo via MFMA with FUSED inter-chunk scan ----------------
// prev(c) built on the fly from raw st chunks: c=0 -> zero (skip MFMA);
// c=1 -> st[chunk0]; c=2 -> st0*dc1 + st1; c=3 -> st0*dc1*dc2 + st1*dc2 + st2.
__global__ __launch_bounds__(256) void yo_combine7(
    const unsigned short* __restrict__ Xbf, const unsigned short* __restrict__ Cbf,
    const unsigned short* __restrict__ st, const float* __restrict__ acs,
    const float* __restrict__ Dp, unsigned short* __restrict__ ybf)
{
  int bid = blockIdx.x;
  int xcd = bid & 7, i0 = bid >> 3;
  int bc = xcd * 8 + (i0 >> 3), h = i0 & 7;
  int c = bc & 3, b = bc >> 2;
  __shared__ float EqA[QLEN];
  const int tid = threadIdx.x;
  const int lane = tid & 63, wv = tid >> 6;
  long rowbase = (long)b * LSEQ + c * QLEN;
  long abase = ((long)b * NH + h) * NCHUNK;
  EqA[tid] = __expf(acs[(abase + c) * QLEN + tid]);
  __syncthreads();
  const unsigned short* Cb = Cbf + rowbase * 128;
  // chunk-state base pointers for this (b,h)
  const long sb0 = ((long)(b * 4 + 0) * 8 + h) * 8192;
  const long sb1 = ((long)(b * 4 + 1) * 8 + h) * 8192;
  const long sb2 = ((long)(b * 4 + 2) * 8 + h) * 8192;
  // scan weights (block-uniform)
  float aend1 = (c >= 2) ? acs[(abase + 1) * QLEN + (QLEN - 1)] : 0.f;
  float aend2 = (c >= 3) ? acs[(abase + 2) * QLEN + (QLEN - 1)] : 0.f;
  float w0 = (c == 2) ? __expf(aend1) : ((c == 3) ? __expf(aend1 + aend2) : 1.f);
  float w1 = (c == 3) ? __expf(aend2) : 1.f;

  f32x4 acc[4][4];
#pragma unroll
  for (int i = 0; i < 4; ++i)
#pragma unroll
    for (int j = 0; j < 4; ++j) acc[i][j] = (f32x4){0.f, 0.f, 0.f, 0.f};
  if (c > 0) {
#pragma unroll
    for (int ks = 0; ks < 4; ++ks) {
      int n0 = ks * 32 + (lane >> 4) * 8;
      s16x8 bf[4];
#pragma unroll
      for (int j = 0; j < 4; ++j) {
        int p = j * 16 + (lane & 15);
        long off = (long)p * 128 + n0;
        if (c == 1) {
          bf[j] = *(const s16x8*)&st[sb0 + off];
        } else if (c == 2) {
          u16x8 s0 = *(const u16x8*)&st[sb0 + off];
          u16x8 s1 = *(const u16x8*)&st[sb1 + off];
#pragma unroll
          for (int k = 0; k < 8; ++k)
            bf[j][k] = (short)f2bf(fmaf(bf2f(s0[k]), w0, bf2f(s1[k])));
        } else {
          u16x8 s0 = *(const u16x8*)&st[sb0 + off];
          u16x8 s1 = *(const u16x8*)&st[sb1 + off];
          u16x8 s2 = *(const u16x8*)&st[sb2 + off];
#pragma unroll
          for (int k = 0; k < 8; ++k)
            bf[j][k] = (short)f2bf(fmaf(bf2f(s0[k]), w0, fmaf(bf2f(s1[k]), w1, bf2f(s2[k]))));
        }
      }
      __builtin_amdgcn_s_setprio(1);
#pragma unroll
      for (int i = 0; i < 4; ++i) {
        s16x8 af = *(const s16x8*)&Cb[(long)(wv * 64 + i * 16 + (lane & 15)) * 128 + n0];
#pragma unroll
        for (int j = 0; j < 4; ++j)
          acc[i][j] = __builtin_amdgcn_mfma_f32_16x16x32_bf16(af, bf[j], acc[i][j], 0, 0, 0);
      }
      __builtin_amdgcn_s_setprio(0);
    }
  }
  const int cr = (lane >> 4) * 4, cc = lane & 15;
  float Dh = Dp[h];
#pragma unroll
  for (int i = 0; i < 4; ++i)
#pragma unroll
    for (int j = 0; j < 4; ++j) {
      int q = wv * 64 + i * 16 + cr;
      int p = j * 16 + cc;
#pragma unroll
      for (int r = 0; r < 4; ++r) {
        long row = rowbase + q + r;
        long yi = row * DIN + h * HD + p;
        float xh = bf2f(Xbf[yi]);
        float pr = bf2f(ybf[yi]);
        ybf[yi] = f2bf(pr + acc[i][j][r] * EqA[q + r] + xh * Dh);
      }
    }
}

// ---------------- gated RMSNorm: wave per row, ushort8; zxb stride ZXW ---------------
__global__ __launch_bounds__(256) void gated_rms4(
    unsigned short* __restrict__ ybf, const unsigned short* __restrict__ zxb,
    const float* __restrict__ rmsw)
{
  long row = (long)blockIdx.x * 4 + (threadIdx.x >> 6);
  int lane = threadIdx.x & 63;
  u16x8 yv = *(const u16x8*)&ybf[row * DIN + lane * 8];
  u16x8 zv = *(const u16x8*)&zxb[row * ZXW + lane * 8];
  float v[8];
  float ss = 0.f;
#pragma unroll
  for (int i = 0; i < 8; ++i) {
    float z = bf2f(zv[i]);
    v[i] = bf2f(yv[i]) * (z / (1.f + __expf(-z)));
    ss = fmaf(v[i], v[i], ss);
  }
#pragma unroll
  for (int off = 32; off; off >>= 1) ss += __shfl_xor(ss, off);
  float scale = rsqrtf(ss * (1.f / DIN) + 1e-5f);
  u16x8 o;
#pragma unroll
  for (int i = 0; i < 8; ++i) {
    float w = rmsw[lane * 8 + i];
    o[i] = f2bf(v[i] * scale * w);
  }
  *(u16x8*)&ybf[row * DIN + lane * 8] = o;
}

// ---------------- LN + classifier: wave per row, no LDS ----------------
__global__ __launch_bounds__(256) void ln_cls2(
    const unsigned short* __restrict__ y2b, const float* __restrict__ g,
    const float* __restrict__ bb, const float* __restrict__ wclsT,
    const float* __restrict__ bcls, float* __restrict__ out)
{
  long row = (long)blockIdx.x * 4 + (threadIdx.x >> 6);
  int lane = threadIdx.x & 63;
  ushort4 yv = *(const ushort4*)&y2b[row * DM + lane * 4];
  float v0 = bf2f(yv.x), v1 = bf2f(yv.y), v2 = bf2f(yv.z), v3 = bf2f(yv.w);
  float s = v0 + v1 + v2 + v3;
  float q = v0 * v0 + v1 * v1 + v2 * v2 + v3 * v3;
#pragma unroll
  for (int off = 32; off; off >>= 1) {
    s += __shfl_xor(s, off);
    q += __shfl_xor(q, off);
  }
  float mu = s * (1.f / DM);
  float rstd = rsqrtf(q * (1.f / DM) - mu * mu + 1e-5f);
  float4 gv = *(const float4*)&g[lane * 4];
  float4 bv = *(const float4*)&bb[lane * 4];
  float y0 = (v0 - mu) * rstd * gv.x + bv.x;
  float y1 = (v1 - mu) * rstd * gv.y + bv.y;
  float y2_ = (v2 - mu) * rstd * gv.z + bv.z;
  float y3 = (v3 - mu) * rstd * gv.w + bv.w;
  float accs[NCLS];
#pragma unroll
  for (int j = 0; j < NCLS; ++j) {
    float4 wv = *(const float4*)&wclsT[j * 256 + lane * 4];
    accs[j] = y0 * wv.x + y1 * wv.y + y2_ * wv.z + y3 * wv.w;
  }
#pragma unroll
  for (int off = 32; off; off >>= 1)
#pragma unroll
    for (int j = 0; j < NCLS; ++j) accs[j] += __shfl_xor(accs[j], off);
  float o = accs[0] + bcls[0];
#pragma unroll
  for (int j = 1; j < NCLS; ++j)
    if (lane == j) o = accs[j] + bcls[j];
  if (lane < NCLS) out[row * NCLS + lane] = o;
}

extern "C" void kernel_launch(void* const* d_in, const int* in_sizes, int n_in,
                              void* d_out, int out_size, void* d_ws, size_t ws_size,
                              hipStream_t stream)
{
  const float* x     = (const float*)d_in[0];
  const float* w_inp = (const float*)d_in[1];
  const float* b_inp = (const float*)d_in[2];
  const float* w_in  = (const float*)d_in[3];
  const float* convw = (const float*)d_in[4];
  const float* convb = (const float*)d_in[5];
  const float* dtb   = (const float*)d_in[6];
  const float* alog  = (const float*)d_in[7];
  const float* Dp    = (const float*)d_in[8];
  const float* rmsw  = (const float*)d_in[9];
  const float* wout  = (const float*)d_in[10];
  const float* lng   = (const float*)d_in[11];
  const float* lnb   = (const float*)d_in[12];
  const float* wcls  = (const float*)d_in[13];
  const float* bcls  = (const float*)d_in[14];
  float* out = (float*)d_out;
  float* ws  = (float*)d_ws;

  float* dtsp = ws + O_DT;
  float* acs  = ws + O_ACS;
  float* Wdt  = ws + O_WDT;
  float* bdt  = Wdt + 1600;
  float* wclsT= ws + O_WCLST;
  unsigned short* Gbf    = (unsigned short*)(ws + O_GBF);
  unsigned short* zxb    = (unsigned short*)(ws + O_ZX);
  unsigned short* Xbf    = (unsigned short*)(ws + O_XBF);
  unsigned short* Bbf    = (unsigned short*)(ws + O_BBF);
  unsigned short* Cbf    = (unsigned short*)(ws + O_CBF);
  unsigned short* BbfT   = (unsigned short*)(ws + O_BT);
  unsigned short* ybf    = (unsigned short*)(ws + O_YBF);
  unsigned short* xp_bf  = (unsigned short*)(ws + O_XPBF);
  unsigned short* WcombT = (unsigned short*)(ws + O_WCT);
  unsigned short* woutT  = (unsigned short*)(ws + O_WOUTT);
  unsigned short* w_inT  = (unsigned short*)(ws + O_WINT);
  unsigned short* we_bf  = (unsigned short*)(ws + O_WIPE);
  unsigned short* st     = (unsigned short*)(ws + O_ST);
  unsigned short* y2b    = (unsigned short*)(ws + O_Y2);

  prep_misc<<<5676, 256, 0, stream>>>(x, xp_bf, w_in, w_inT, wout, woutT,
                                      w_inp, b_inp, we_bf, Wdt, bdt, wcls, wclsT);
  gemm_bf16<<<dim3(2, 11), 256, 0, stream>>>(w_inT, we_bf, nullptr, WcombT, nullptr, 1408, 224, 256);
  gemm_bf16<<<dim3(10, 128), 256, 0, stream>>>(xp_bf, WcombT, nullptr, zxb, nullptr, 16384, ZXW, 224);
  conv_silu5<<<1536, 256, 0, stream>>>(zxb, convw, convb, Xbf, Bbf, Cbf);
  dt_logits<<<512, 256, 0, stream>>>(x, Wdt, bdt, dtb, dtsp);
  dt_cumsum4<<<128, 256, 0, stream>>>(dtsp, alog, acs);
  trans_g<<<384, 256, 0, stream>>>(Bbf, BbfT, Cbf, Gbf);
  yd_states7<<<1024, 256, 0, stream>>>(Xbf, dtsp, acs, Gbf, BbfT, ybf, st);
  yo_combine7<<<512, 256, 0, stream>>>(Xbf, Cbf, st, acs, Dp, ybf);
  gated_rms4<<<4096, 256, 0, stream>>>(ybf, zxb, rmsw);
  gemm_bf16<<<dim3(2, 128), 256, 0, stream>>>(ybf, woutT, nullptr, y2b, nullptr, 16384, DM, DIN);
  ln_cls2<<<4096, 256, 0, stream>>>(y2b, lng, lnb, wclsT, bcls, out);
}

// Round 17
// 184.445 us; speedup vs baseline: 1.0206x; 1.0206x over previous
//
#include <hip/hip_runtime.h>
#include <math.h>

#define ROWS   16384L
#define LSEQ   1024
#define NB     16
#define DM     256
#define DPROJ  1288
#define ZXW    1280          // zxb leading dim (dt cols dropped)
#define XBCW   768
#define DIN    512
#define DSTATE 128
#define NH     8
#define HD     64
#define QLEN   256
#define NCHUNK 4
#define NCLS   17

typedef __attribute__((ext_vector_type(8))) short s16x8;
typedef __attribute__((ext_vector_type(8))) unsigned short u16x8;
typedef __attribute__((ext_vector_type(4))) float f32x4;

#define GLOAD_LDS16(gsrc, ldst) \
  __builtin_amdgcn_global_load_lds((const __attribute__((address_space(1))) void*)(gsrc), \
      (__attribute__((address_space(3))) void*)(ldst), 16, 0, 0)

// ---- workspace map (float slots) ----
constexpr long O_GBF  = 0;
constexpr long O_ZX   = O_GBF + ROWS*DM;          // zxb bf16 [ROWS][1280]
constexpr long O_XBC  = O_ZX  + ROWS*DPROJ;
constexpr long O_DT   = O_XBC + ROWS*XBCW;
constexpr long O_ACS  = O_DT  + ROWS*NH;
constexpr long O_Y    = O_ACS + 131072;
constexpr long O_ST   = O_Y   + ROWS*DIN;         // st bf16 [512][64p][128n]
constexpr long O_Y2   = O_ST  + 4194304;
constexpr long O_XBF  = O_XBC;
constexpr long O_BBF  = O_XBC + 4200000;
constexpr long O_CBF  = O_XBC + 5300000;
constexpr long O_BT   = O_XBC + 6400000;
constexpr long O_YBF  = O_Y;
constexpr long O_XPBF = O_Y + 4300000;
constexpr long O_WCT  = O_Y + 6200000;
constexpr long O_WOUTT= O_Y + 6400000;
constexpr long O_WDT  = O_Y + 6500000;
constexpr long O_WCLST= O_Y + 6530000;
constexpr long O_WINT = O_Y + 6600000;
constexpr long O_WIPE = O_Y + 6800000;

__device__ inline unsigned short f2bf(float f) {
  union { float f; unsigned u; } v; v.f = f;
  unsigned r = v.u + 0x7FFFu + ((v.u >> 16) & 1u);
  return (unsigned short)(r >> 16);
}
__device__ inline float bf2f(unsigned short s) {
  union { unsigned u; float f; } v; v.u = ((unsigned)s) << 16; return v.f;
}

// bijective XCD-chunked swizzle (m204)
__device__ inline void xcd_swizzle(int gx, int& bx, int& by) {
  int nwg = gx * (int)gridDim.y;
  int lid = (int)blockIdx.y * gx + (int)blockIdx.x;
  int q = nwg >> 3, r = nwg & 7;
  int xcd = lid & 7, idx = lid >> 3;
  int base = xcd < r ? xcd * (q + 1) : r * (q + 1) + (xcd - r) * q;
  int w = base + idx;
  bx = w % gx; by = w / gx;
}

// ---------------- merged prep: block-range dispatch over 6 roles ----------------
__global__ __launch_bounds__(256) void prep_misc(
    const float* __restrict__ x, unsigned short* __restrict__ xp,
    const float* __restrict__ w_in, unsigned short* __restrict__ w_inT,
    const float* __restrict__ wout, unsigned short* __restrict__ woutT,
    const float* __restrict__ w_inp, const float* __restrict__ b_inp,
    unsigned short* __restrict__ we,
    float* __restrict__ Wdt, float* __restrict__ bdt,
    const float* __restrict__ wcls, float* __restrict__ wclsT)
{
  int bid = blockIdx.x;
  int tid = threadIdx.x;
  if (bid < 3584) {                                      // cast_pad_x (col 200 = 1.0)
    long idx = (long)bid * 256 + tid;
    int q = (int)(idx % 56);
    long row = idx / 56;
    ushort4 o = {0, 0, 0, 0};
    if (q < 50) {
      float4 v = *(const float4*)&x[row * 200 + q * 4];
      o.x = f2bf(v.x); o.y = f2bf(v.y); o.z = f2bf(v.z); o.w = f2bf(v.w);
    } else if (q == 50) {
      o.x = 0x3F80;
    }
    *(ushort4*)&xp[row * 224 + q * 4] = o;
  } else if (bid < 4872) {                               // tcast w_in -> w_inT [n][256]
    long i = (long)(bid - 3584) * 256 + tid;
    int k = (int)(i & 255);
    long n = i >> 8;
    w_inT[i] = f2bf(w_in[(long)k * DPROJ + n]);
  } else if (bid < 5384) {                               // tcast wout -> woutT [n][512]
    long i = (long)(bid - 4872) * 256 + tid;
    int k = (int)(i & 511);
    long n = i >> 9;
    woutT[i] = f2bf(wout[(long)k * DM + n]);
  } else if (bid < 5608) {                               // cast_winp_ext [224][256]
    int i = (bid - 5384) * 256 + tid;
    int k = i >> 8, j = i & 255;
    float v = 0.f;
    if (k < 200)       v = w_inp[(long)k * 256 + j];
    else if (k == 200) v = b_inp[j];
    we[i] = f2bf(v);
  } else if (bid < 5659) {                               // wdt_small (exact f32 dt weights)
    int k = (bid - 5608) * 4 + (tid >> 6);
    if (k > 200) return;
    int lane = tid & 63;
    int j0 = lane * 4;
    float4 xv = (k < 200) ? *(const float4*)&w_inp[(long)k * 256 + j0]
                          : *(const float4*)&b_inp[j0];
    float a0 = 0.f, a1 = 0.f, a2 = 0.f, a3 = 0.f, a4 = 0.f, a5 = 0.f, a6 = 0.f, a7 = 0.f;
    float xd[4] = {xv.x, xv.y, xv.z, xv.w};
#pragma unroll
    for (int d = 0; d < 4; ++d) {
      const float* wr = &w_in[(long)(j0 + d) * DPROJ + 1280];
      float4 wa = *(const float4*)wr;
      float4 wb = *(const float4*)(wr + 4);
      a0 = fmaf(xd[d], wa.x, a0); a1 = fmaf(xd[d], wa.y, a1);
      a2 = fmaf(xd[d], wa.z, a2); a3 = fmaf(xd[d], wa.w, a3);
      a4 = fmaf(xd[d], wb.x, a4); a5 = fmaf(xd[d], wb.y, a5);
      a6 = fmaf(xd[d], wb.z, a6); a7 = fmaf(xd[d], wb.w, a7);
    }
#pragma unroll
    for (int off = 32; off; off >>= 1) {
      a0 += __shfl_xor(a0, off); a1 += __shfl_xor(a1, off);
      a2 += __shfl_xor(a2, off); a3 += __shfl_xor(a3, off);
      a4 += __shfl_xor(a4, off); a5 += __shfl_xor(a5, off);
      a6 += __shfl_xor(a6, off); a7 += __shfl_xor(a7, off);
    }
    float o = a0;
    if (lane == 1) o = a1; if (lane == 2) o = a2; if (lane == 3) o = a3;
    if (lane == 4) o = a4; if (lane == 5) o = a5; if (lane == 6) o = a6;
    if (lane == 7) o = a7;
    if (lane < 8) {
      if (k < 200) Wdt[k * 8 + lane] = o;
      else         bdt[lane] = o;
    }
  } else {                                               // tpose_wcls
    int i = (bid - 5659) * 256 + tid;
    if (i < NCLS * 256) {
      int j = i >> 8, k = i & 255;
      wclsT[i] = wcls[(long)k * NCLS + j];
    }
  }
}

// ---------------- bf16 MFMA GEMM (global_load_lds staging + XCD swizzle) -------------
__global__ __launch_bounds__(256) void gemm_bf16(
    const unsigned short* __restrict__ A, const unsigned short* __restrict__ BT,
    float* __restrict__ C, unsigned short* __restrict__ Cb,
    const float* __restrict__ bias, int M, int N, int K)
{
  int bx, by;
  xcd_swizzle(gridDim.x, bx, by);
  __shared__ __align__(16) unsigned short As[128 * 32];
  __shared__ __align__(16) unsigned short Bs[128 * 32];
  const int tid = threadIdx.x;
  const int m0 = by * 128, n0 = bx * 128;
  const int lane = tid & 63, wv = tid >> 6;
  const int wr = (wv >> 1) * 64, wc = (wv & 1) * 64;
  f32x4 acc[4][4];
#pragma unroll
  for (int i = 0; i < 4; ++i)
#pragma unroll
    for (int j = 0; j < 4; ++j) acc[i][j] = (f32x4){0.f, 0.f, 0.f, 0.f};

  for (int k0 = 0; k0 < K; k0 += 32) {
    __syncthreads();
#pragma unroll
    for (int s = 0; s < 2; ++s) {
      int idx = (tid + 256 * s) * 8;
      int r = idx >> 5, kk = idx & 31;
      GLOAD_LDS16(&A[(long)(m0 + r) * K + k0 + kk], &As[idx]);
    }
#pragma unroll
    for (int s = 0; s < 2; ++s) {
      int idx = (tid + 256 * s) * 8;
      int n = idx >> 5, kk = idx & 31;
      int srcn = (n0 + n < N) ? (n0 + n) : 0;
      GLOAD_LDS16(&BT[(long)srcn * K + k0 + kk], &Bs[idx]);
    }
    __syncthreads();
    s16x8 af[4], bf[4];
#pragma unroll
    for (int i = 0; i < 4; ++i)
      af[i] = *(const s16x8*)&As[(wr + i * 16 + (lane & 15)) * 32 + (lane >> 4) * 8];
#pragma unroll
    for (int j = 0; j < 4; ++j)
      bf[j] = *(const s16x8*)&Bs[(wc + j * 16 + (lane & 15)) * 32 + (lane >> 4) * 8];
    __builtin_amdgcn_s_setprio(1);
#pragma unroll
    for (int i = 0; i < 4; ++i)
#pragma unroll
      for (int j = 0; j < 4; ++j)
        acc[i][j] = __builtin_amdgcn_mfma_f32_16x16x32_bf16(af[i], bf[j], acc[i][j], 0, 0, 0);
    __builtin_amdgcn_s_setprio(0);
  }
  const int cr = (lane >> 4) * 4, cc = lane & 15;
#pragma unroll
  for (int i = 0; i < 4; ++i)
#pragma unroll
    for (int j = 0; j < 4; ++j) {
      int col = n0 + wc + j * 16 + cc;
      if (col < N) {
        long rowb = (long)(m0 + wr + i * 16 + cr);
        float bv = bias ? bias[col] : 0.f;
#pragma unroll
        for (int r = 0; r < 4; ++r) {
          float v = acc[i][j][r] + bv;
          if (C)  C[(rowb + r) * N + col] = v;
          if (Cb) Cb[(rowb + r) * (long)N + col] = f2bf(v);
        }
      }
    }
}

// ---------------- merged transB + G-GEMM (block-range dispatch) ----------------
__global__ __launch_bounds__(256) void trans_g(
    const unsigned short* __restrict__ Bbf, unsigned short* __restrict__ BbfT,
    const unsigned short* __restrict__ Cbf, unsigned short* __restrict__ Gbf)
{
  const int bid = blockIdx.x;
  const int tid = threadIdx.x;
  if (bid < 128) {                                   // ---- transB ----
    __shared__ unsigned short T[128][130];
    int bc = bid >> 1, kh = bid & 1;
    long rowbase = (long)(bc >> 2) * LSEQ + (bc & 3) * QLEN + kh * 128;
    for (int e = tid; e < 128 * 128; e += 256) {
      int r = e >> 7, n = e & 127;
      T[r][n] = Bbf[(rowbase + r) * 128 + n];
    }
    __syncthreads();
    for (int e = tid; e < 128 * 128; e += 256) {
      int n = e >> 7, k = e & 127;
      BbfT[((long)bc * 128 + n) * 256 + kh * 128 + k] = T[k][n];
    }
    return;
  }
  if (bid >= 320) {                                  // ---- zero upper tile (m0=0,n0=128) ----
    int bc = bid - 320;
    unsigned short* Gout = Gbf + (long)bc * 65536;
    s16x8 z = {};
    for (int e = tid; e < 128 * 16; e += 256) {
      int r = e >> 4, seg = e & 15;
      *(s16x8*)&Gout[(long)r * 256 + 128 + seg * 8] = z;
    }
    return;
  }
  int bid2 = bid - 128;
  int t = bid2 % 3, bc = bid2 / 3;
  int m0 = (t == 0) ? 0 : 128;
  int n0 = (t == 2) ? 128 : 0;
  unsigned short* Gout = Gbf + (long)bc * 65536;
  long rowbase = (long)(bc >> 2) * LSEQ + (bc & 3) * QLEN;
  const unsigned short* A  = Cbf + rowbase * 128;
  const unsigned short* BT = Bbf + rowbase * 128;
  __shared__ __align__(16) unsigned short As[128 * 32];
  __shared__ __align__(16) unsigned short Bs[128 * 32];
  const int lane = tid & 63, wv = tid >> 6;
  const int wr = (wv >> 1) * 64, wc = (wv & 1) * 64;
  f32x4 acc[4][4];
#pragma unroll
  for (int i = 0; i < 4; ++i)
#pragma unroll
    for (int j = 0; j < 4; ++j) acc[i][j] = (f32x4){0.f, 0.f, 0.f, 0.f};
  for (int k0 = 0; k0 < 128; k0 += 32) {
    __syncthreads();
#pragma unroll
    for (int s = 0; s < 2; ++s) {
      int idx = (tid + 256 * s) * 8;
      int r = idx >> 5, kk = idx & 31;
      GLOAD_LDS16(&A[(long)(m0 + r) * 128 + k0 + kk], &As[idx]);
      GLOAD_LDS16(&BT[(long)(n0 + r) * 128 + k0 + kk], &Bs[idx]);
    }
    __syncthreads();
    s16x8 af[4], bf[4];
#pragma unroll
    for (int i = 0; i < 4; ++i)
      af[i] = *(const s16x8*)&As[(wr + i * 16 + (lane & 15)) * 32 + (lane >> 4) * 8];
#pragma unroll
    for (int j = 0; j < 4; ++j)
      bf[j] = *(const s16x8*)&Bs[(wc + j * 16 + (lane & 15)) * 32 + (lane >> 4) * 8];
    __builtin_amdgcn_s_setprio(1);
#pragma unroll
    for (int i = 0; i < 4; ++i)
#pragma unroll
      for (int j = 0; j < 4; ++j)
        acc[i][j] = __builtin_amdgcn_mfma_f32_16x16x32_bf16(af[i], bf[j], acc[i][j], 0, 0, 0);
    __builtin_amdgcn_s_setprio(0);
  }
  const int cr = (lane >> 4) * 4, cc = lane & 15;
#pragma unroll
  for (int i = 0; i < 4; ++i)
#pragma unroll
    for (int j = 0; j < 4; ++j) {
      int col = n0 + wc + j * 16 + cc;
      int qb = m0 + wr + i * 16 + cr;
#pragma unroll
      for (int r = 0; r < 4; ++r)
        Gout[(long)(qb + r) * 256 + col] = (col <= qb + r) ? f2bf(acc[i][j][r]) : (unsigned short)0;
    }
}

// ---------------- conv1d (k=4, causal) + SiLU: 4-timestep x 8-channel tiles ----------
__global__ __launch_bounds__(256) void conv_silu5(
    const unsigned short* __restrict__ zxb, const float* __restrict__ cw,
    const float* __restrict__ cb,
    unsigned short* __restrict__ Xbf, unsigned short* __restrict__ Bbf,
    unsigned short* __restrict__ Cbf)
{
  long idx = (long)blockIdx.x * 256 + threadIdx.x;
  if (idx >= (ROWS / 4) * 96) return;
  int co = (int)(idx % 96);
  long tmp = idx / 96;
  int tq = (int)(tmp & 255);
  int b = (int)(tmp >> 8);
  int ch = co * 8;
  long row0 = (long)b * LSEQ + tq * 4;
  u16x8 zv[7];
#pragma unroll
  for (int j = 0; j < 7; ++j) {
    if (j >= 3 || tq > 0)
      zv[j] = *(const u16x8*)&zxb[(row0 + j - 3) * ZXW + 512 + ch];
    else
      zv[j] = (u16x8){0, 0, 0, 0, 0, 0, 0, 0};
  }
  float cwv[4][8], cbv[8];
  {
    float4 b0 = *(const float4*)&cb[ch];
    float4 b1 = *(const float4*)&cb[ch + 4];
    cbv[0] = b0.x; cbv[1] = b0.y; cbv[2] = b0.z; cbv[3] = b0.w;
    cbv[4] = b1.x; cbv[5] = b1.y; cbv[6] = b1.z; cbv[7] = b1.w;
  }
#pragma unroll
  for (int w = 0; w < 4; ++w) {
    float4 c0 = *(const float4*)&cw[w * XBCW + ch];
    float4 c1 = *(const float4*)&cw[w * XBCW + ch + 4];
    cwv[w][0] = c0.x; cwv[w][1] = c0.y; cwv[w][2] = c0.z; cwv[w][3] = c0.w;
    cwv[w][4] = c1.x; cwv[w][5] = c1.y; cwv[w][6] = c1.z; cwv[w][7] = c1.w;
  }
#pragma unroll
  for (int i = 0; i < 4; ++i) {
    float a[8];
#pragma unroll
    for (int k = 0; k < 8; ++k) a[k] = cbv[k];
#pragma unroll
    for (int w = 0; w < 4; ++w) {
#pragma unroll
      for (int k = 0; k < 8; ++k)
        a[k] = fmaf(bf2f(zv[i + w][k]), cwv[w][k], a[k]);
    }
    u16x8 o;
#pragma unroll
    for (int k = 0; k < 8; ++k)
      o[k] = f2bf(a[k] / (1.f + __expf(-a[k])));
    long row = row0 + i;
    if (ch < 512)      *(u16x8*)&Xbf[row * DIN + ch] = o;
    else if (ch < 640) *(u16x8*)&Bbf[row * 128 + ch - 512] = o;
    else               *(u16x8*)&Cbf[row * 128 + ch - 640] = o;
  }
}

// ---------------- dt logits: block = 32 rows, LDS-staged x and Wdt; f32-exact --------
__global__ __launch_bounds__(256) void dt_logits(
    const float* __restrict__ x, const float* __restrict__ Wdt,
    const float* __restrict__ bdt, const float* __restrict__ dtb,
    float* __restrict__ dtsp)
{
  __shared__ float xs[32][201];
  __shared__ float wdt_s[1600];
  long row0 = (long)blockIdx.x * 32;
  int tid = threadIdx.x;
#pragma unroll
  for (int s = 0; s < 25; ++s) {
    int e = tid + s * 256;
    int r = e / 200, c = e % 200;
    xs[r][c] = x[(row0 + r) * 200 + c];
  }
#pragma unroll
  for (int s = 0; s < 7; ++s) {
    int e = tid + s * 256;
    if (e < 1600) wdt_s[e] = Wdt[e];
  }
  __syncthreads();
  int r = tid >> 3, h = tid & 7;
  float acc = dtb[h] + bdt[h];
  for (int i = 0; i < 200; ++i)
    acc = fmaf(xs[r][i], wdt_s[i * 8 + h], acc);
  float sp = (acc > 20.f) ? acc : log1pf(__expf(acc));
  dtsp[(row0 + r) * NH + h] = sp;
}

// ---------------- cumsum only: wave per (b,h,c) ----------------
__global__ __launch_bounds__(256) void dt_cumsum4(
    const float* __restrict__ dtsp, const float* __restrict__ alog,
    float* __restrict__ acs)
{
  int g = ((int)blockIdx.x * 256 + (int)threadIdx.x) >> 6;
  int lane = threadIdx.x & 63;
  int c = g & 3, h = (g >> 2) & 7, b = g >> 5;
  float Ah = -__expf(alog[h]);
  long rowbase = (long)b * LSEQ + c * QLEN;
  long abase = (((long)b * NH + h) * NCHUNK + c) * QLEN;
  float v[4];
#pragma unroll
  for (int j = 0; j < 4; ++j)
    v[j] = dtsp[(rowbase + lane * 4 + j) * NH + h] * Ah;
  v[1] += v[0]; v[2] += v[1]; v[3] += v[2];
  float tot = v[3];
  float run = tot;
#pragma unroll
  for (int d = 1; d < 64; d <<= 1) {
    float t = __shfl_up(run, d);
    if (lane >= d) run += t;
  }
  float excl = run - tot;
#pragma unroll
  for (int j = 0; j < 4; ++j) acs[abase + lane * 4 + j] = excl + v[j];
}

// ---------------- yd+states: balanced q-block split {0,3}/{1,2}; bf16 st -------------
__global__ __launch_bounds__(256) void yd_states7(
    const unsigned short* __restrict__ Xbf, const float* __restrict__ dtsp,
    const float* __restrict__ acs, const unsigned short* __restrict__ Gbf,
    const unsigned short* __restrict__ BbfT,
    unsigned short* __restrict__ ybf, unsigned short* __restrict__ st)
{
  int bid = blockIdx.x;
  int xcd = bid & 7, i0 = bid >> 3;
  int bc = xcd * 8 + (i0 >> 4);
  int rem = i0 & 15, h = rem >> 1, half = rem & 1;
  int c = bc & 3, b = bc >> 2;
  int bch = bc * 8 + h;

  __shared__ __align__(16) unsigned short XdT[64][264];
  __shared__ float AcsS[256], E1f[256], E2f[256], dts[256];

  const int tid = threadIdx.x;
  const int lane = tid & 63, wv = tid >> 6;
  const bool ydw = wv < 2;
  const int qb = half == 0 ? (wv == 0 ? 0 : 3) : (wv == 0 ? 1 : 2);
  const int q0 = qb * 64;
  const int n0w = half * 64 + (wv - 2) * 32;
  long rowbase = (long)b * LSEQ + c * QLEN;
  const unsigned short* Gb  = Gbf + (long)bc * 65536;
  const unsigned short* BTg = BbfT + (long)bc * 32768;

  AcsS[tid] = acs[(((long)b * NH + h) * NCHUNK + c) * QLEN + tid];
  dts[tid]  = dtsp[(rowbase + tid) * NH + h];
  __syncthreads();
  E1f[tid] = __expf(AcsS[tid] - AcsS[tid | 63]);
  E2f[tid] = __expf(AcsS[tid | 63] - AcsS[tid]);
  float rs_[4];
  rs_[0] = 1.f;
#pragma unroll
  for (int kt = 1; kt < 4; ++kt) rs_[kt] = __expf(AcsS[kt * 64 + 63] - AcsS[kt * 64 - 1]);
  __syncthreads();
  {
    int kb = wv * 64;
#pragma unroll
    for (int s = 0; s < 16; ++s) {
      int k4 = kb + s * 4;
      ushort4 pk;
      unsigned short* pp = (unsigned short*)&pk;
#pragma unroll
      for (int j = 0; j < 4; ++j) {
        int k = k4 + j;
        float v = bf2f(Xbf[(rowbase + k) * DIN + h * HD + lane]) * dts[k] * E2f[k];
        pp[j] = f2bf(v);
      }
      *(ushort4*)&XdT[lane][k4] = pk;
    }
  }
  __syncthreads();

  f32x4 accY[4][4], accS[4][2];
#pragma unroll
  for (int i = 0; i < 4; ++i)
#pragma unroll
    for (int j = 0; j < 4; ++j) accY[i][j] = (f32x4){0.f, 0.f, 0.f, 0.f};
#pragma unroll
  for (int i = 0; i < 4; ++i)
#pragma unroll
    for (int j = 0; j < 2; ++j) accS[i][j] = (f32x4){0.f, 0.f, 0.f, 0.f};

  for (int kt = 0; kt < 4; ++kt) {
    int qlo = kt * 64;
    if (ydw) {
      if (qb >= kt) {
        if (kt)
#pragma unroll
          for (int i = 0; i < 4; ++i)
#pragma unroll
            for (int j = 0; j < 4; ++j) accY[i][j] *= rs_[kt];
#pragma unroll
        for (int ks = 0; ks < 2; ++ks) {
          s16x8 bfr[4];
#pragma unroll
          for (int j = 0; j < 4; ++j)
            bfr[j] = *(const s16x8*)&XdT[j * 16 + (lane & 15)][qlo + ks * 32 + (lane >> 4) * 8];
          __builtin_amdgcn_s_setprio(1);
#pragma unroll
          for (int i = 0; i < 4; ++i) {
            s16x8 a = *(const s16x8*)&Gb[(long)(q0 + i * 16 + (lane & 15)) * 256 + qlo + ks * 32 + (lane >> 4) * 8];
#pragma unroll
            for (int j = 0; j < 4; ++j)
              accY[i][j] = __builtin_amdgcn_mfma_f32_16x16x32_bf16(a, bfr[j], accY[i][j], 0, 0, 0);
          }
          __builtin_amdgcn_s_setprio(0);
        }
      }
    } else {
      if (kt)
#pragma unroll
        for (int i = 0; i < 4; ++i)
#pragma unroll
          for (int j = 0; j < 2; ++j) accS[i][j] *= rs_[kt];
#pragma unroll
      for (int ks = 0; ks < 2; ++ks) {
        s16x8 afx[4];
#pragma unroll
        for (int i = 0; i < 4; ++i)
          afx[i] = *(const s16x8*)&XdT[i * 16 + (lane & 15)][qlo + ks * 32 + (lane >> 4) * 8];
        __builtin_amdgcn_s_setprio(1);
#pragma unroll
        for (int j2 = 0; j2 < 2; ++j2) {
          s16x8 bt = *(const s16x8*)&BTg[(long)(n0w + j2 * 16 + (lane & 15)) * 256 + qlo + ks * 32 + (lane >> 4) * 8];
#pragma unroll
          for (int i = 0; i < 4; ++i)
            accS[i][j2] = __builtin_amdgcn_mfma_f32_16x16x32_bf16(afx[i], bt, accS[i][j2], 0, 0, 0);
        }
        __builtin_amdgcn_s_setprio(0);
      }
    }
  }
  const int cr = (lane >> 4) * 4, cc = lane & 15;
  if (ydw) {
#pragma unroll
    for (int i = 0; i < 4; ++i)
#pragma unroll
      for (int j = 0; j < 4; ++j) {
        int q = q0 + i * 16 + cr;
        int p = j * 16 + cc;
#pragma unroll
        for (int r = 0; r < 4; ++r)
          ybf[(rowbase + q + r) * DIN + h * HD + p] = f2bf(accY[i][j][r] * E1f[q + r]);
      }
  } else {
#pragma unroll
    for (int i = 0; i < 4; ++i)
#pragma unroll
      for (int j2 = 0; j2 < 2; ++j2) {
        int p = i * 16 + cr;
        int n = n0w + j2 * 16 + cc;
#pragma unroll
        for (int r = 0; r < 4; ++r)
          st[(long)bch * 8192 + (long)(p + r) * 128 + n] = f2bf(accS[i][j2][r]);
      }
  }
}

// ---------------- inter-chunk scan (bf16 storage, f32 carry) ----------------
__global__ void scan_states(unsigned short* __restrict__ st, const float* __restrict__ acs)
{
  long idx = (long)blockIdx.x * 256 + threadIdx.x;
  if (idx >= (long)NB * NH * 2048) return;
  long inner = idx & 2047;
  int h = (int)((idx >> 11) & 7);
  int b = (int)(idx >> 14);
  f32x4 carry = {0.f, 0.f, 0.f, 0.f};
  for (int c = 0; c < NCHUNK; ++c) {
    float dc = __expf(acs[(((long)b * NH + h) * NCHUNK + c) * QLEN + (QLEN - 1)]);
    long si = (((long)(b * NCHUNK + c) * NH + h) << 13) + inner * 4;
    ushort4 s4 = *(ushort4*)&st[si];
    f32x4 s = {bf2f(s4.x), bf2f(s4.y), bf2f(s4.z), bf2f(s4.w)};
    ushort4 o = {f2bf(carry[0]), f2bf(carry[1]), f2bf(carry[2]), f2bf(carry[3])};
    *(ushort4*)&st[si] = o;
    carry = carry * dc + s;
  }
}

// ---------------- Yo via MFMA: prev bf16 direct operand ----------------
__global__ __launch_bounds__(256) void yo_combine6(
    const unsigned short* __restrict__ Xbf, const unsigned short* __restrict__ Cbf,
    const unsigned short* __restrict__ prev, const float* __restrict__ acs,
    const float* __restrict__ Dp, unsigned short* __restrict__ ybf)
{
  int bid = blockIdx.x;
  int xcd = bid & 7, i0 = bid >> 3;
  int bc = xcd * 8 + (i0 >> 3), h = i0 & 7;
  int c = bc & 3, b = bc >> 2;
  int bch = bc * 8 + h;
  __shared__ float EqA[QLEN];
  const int tid = threadIdx.x;
  const int lane = tid & 63, wv = tid >> 6;
  long rowbase = (long)b * LSEQ + c * QLEN;
  EqA[tid] = __expf(acs[(((long)b * NH + h) * NCHUNK + c) * QLEN + tid]);
  __syncthreads();
  const unsigned short* Cb = Cbf + rowbase * 128;
  const unsigned short* pv = prev + (long)bch * 8192;
  f32x4 acc[4][4];
#pragma unroll
  for (int i = 0; i < 4; ++i)
#pragma unroll
    for (int j = 0; j < 4; ++j) acc[i][j] = (f32x4){0.f, 0.f, 0.f, 0.f};
#pragma unroll
  for (int ks = 0; ks < 4; ++ks) {
    int n0 = ks * 32 + (lane >> 4) * 8;
    s16x8 bf[4];
#pragma unroll
    for (int j = 0; j < 4; ++j) {
      int p = j * 16 + (lane & 15);
      bf[j] = *(const s16x8*)&pv[p * 128 + n0];
    }
    __builtin_amdgcn_s_setprio(1);
#pragma unroll
    for (int i = 0; i < 4; ++i) {
      s16x8 af = *(const s16x8*)&Cb[(long)(wv * 64 + i * 16 + (lane & 15)) * 128 + n0];
#pragma unroll
      for (int j = 0; j < 4; ++j)
        acc[i][j] = __builtin_amdgcn_mfma_f32_16x16x32_bf16(af, bf[j], acc[i][j], 0, 0, 0);
    }
    __builtin_amdgcn_s_setprio(0);
  }
  const int cr = (lane >> 4) * 4, cc = lane & 15;
  float Dh = Dp[h];
#pragma unroll
  for (int i = 0; i < 4; ++i)
#pragma unroll
    for (int j = 0; j < 4; ++j) {
      int q = wv * 64 + i * 16 + cr;
      int p = j * 16 + cc;
#pragma unroll
      for (int r = 0; r < 4; ++r) {
        long row = rowbase + q + r;
        long yi = row * DIN + h * HD + p;
        float xh = bf2f(Xbf[yi]);
        float pr = bf2f(ybf[yi]);
        ybf[yi] = f2bf(pr + acc[i][j][r] * EqA[q + r] + xh * Dh);
      }
    }
}

// ---------------- gated RMSNorm: wave per row, ushort8; zxb stride ZXW ---------------
__global__ __launch_bounds__(256) void gated_rms4(
    unsigned short* __restrict__ ybf, const unsigned short* __restrict__ zxb,
    const float* __restrict__ rmsw)
{
  long row = (long)blockIdx.x * 4 + (threadIdx.x >> 6);
  int lane = threadIdx.x & 63;
  u16x8 yv = *(const u16x8*)&ybf[row * DIN + lane * 8];
  u16x8 zv = *(const u16x8*)&zxb[row * ZXW + lane * 8];
  float v[8];
  float ss = 0.f;
#pragma unroll
  for (int i = 0; i < 8; ++i) {
    float z = bf2f(zv[i]);
    v[i] = bf2f(yv[i]) * (z / (1.f + __expf(-z)));
    ss = fmaf(v[i], v[i], ss);
  }
#pragma unroll
  for (int off = 32; off; off >>= 1) ss += __shfl_xor(ss, off);
  float scale = rsqrtf(ss * (1.f / DIN) + 1e-5f);
  u16x8 o;
#pragma unroll
  for (int i = 0; i < 8; ++i) {
    float w = rmsw[lane * 8 + i];
    o[i] = f2bf(v[i] * scale * w);
  }
  *(u16x8*)&ybf[row * DIN + lane * 8] = o;
}

// ---------------- LN + classifier: wave per row, no LDS ----------------
__global__ __launch_bounds__(256) void ln_cls2(
    const unsigned short* __restrict__ y2b, const float* __restrict__ g,
    const float* __restrict__ bb, const float* __restrict__ wclsT,
    const float* __restrict__ bcls, float* __restrict__ out)
{
  long row = (long)blockIdx.x * 4 + (threadIdx.x >> 6);
  int lane = threadIdx.x & 63;
  ushort4 yv = *(const ushort4*)&y2b[row * DM + lane * 4];
  float v0 = bf2f(yv.x), v1 = bf2f(yv.y), v2 = bf2f(yv.z), v3 = bf2f(yv.w);
  float s = v0 + v1 + v2 + v3;
  float q = v0 * v0 + v1 * v1 + v2 * v2 + v3 * v3;
#pragma unroll
  for (int off = 32; off; off >>= 1) {
    s += __shfl_xor(s, off);
    q += __shfl_xor(q, off);
  }
  float mu = s * (1.f / DM);
  float rstd = rsqrtf(q * (1.f / DM) - mu * mu + 1e-5f);
  float4 gv = *(const float4*)&g[lane * 4];
  float4 bv = *(const float4*)&bb[lane * 4];
  float y0 = (v0 - mu) * rstd * gv.x + bv.x;
  float y1 = (v1 - mu) * rstd * gv.y + bv.y;
  float y2_ = (v2 - mu) * rstd * gv.z + bv.z;
  float y3 = (v3 - mu) * rstd * gv.w + bv.w;
  float accs[NCLS];
#pragma unroll
  for (int j = 0; j < NCLS; ++j) {
    float4 wv = *(const float4*)&wclsT[j * 256 + lane * 4];
    accs[j] = y0 * wv.x + y1 * wv.y + y2_ * wv.z + y3 * wv.w;
  }
#pragma unroll
  for (int off = 32; off; off >>= 1)
#pragma unroll
    for (int j = 0; j < NCLS; ++j) accs[j] += __shfl_xor(accs[j], off);
  float o = accs[0] + bcls[0];
#pragma unroll
  for (int j = 1; j < NCLS; ++j)
    if (lane == j) o = accs[j] + bcls[j];
  if (lane < NCLS) out[row * NCLS + lane] = o;
}

extern "C" void kernel_launch(void* const* d_in, const int* in_sizes, int n_in,
                              void* d_out, int out_size, void* d_ws, size_t ws_size,
                              hipStream_t stream)
{
  const float* x     = (const float*)d_in[0];
  const float* w_inp = (const float*)d_in[1];
  const float* b_inp = (const float*)d_in[2];
  const float* w_in  = (const float*)d_in[3];
  const float* convw = (const float*)d_in[4];
  const float* convb = (const float*)d_in[5];
  const float* dtb   = (const float*)d_in[6];
  const float* alog  = (const float*)d_in[7];
  const float* Dp    = (const float*)d_in[8];
  const float* rmsw  = (const float*)d_in[9];
  const float* wout  = (const float*)d_in[10];
  const float* lng   = (const float*)d_in[11];
  const float* lnb   = (const float*)d_in[12];
  const float* wcls  = (const float*)d_in[13];
  const float* bcls  = (const float*)d_in[14];
  float* out = (float*)d_out;
  float* ws  = (float*)d_ws;

  float* dtsp = ws + O_DT;
  float* acs  = ws + O_ACS;
  float* Wdt  = ws + O_WDT;
  float* bdt  = Wdt + 1600;
  float* wclsT= ws + O_WCLST;
  unsigned short* Gbf    = (unsigned short*)(ws + O_GBF);
  unsigned short* zxb    = (unsigned short*)(ws + O_ZX);
  unsigned short* Xbf    = (unsigned short*)(ws + O_XBF);
  unsigned short* Bbf    = (unsigned short*)(ws + O_BBF);
  unsigned short* Cbf    = (unsigned short*)(ws + O_CBF);
  unsigned short* BbfT   = (unsigned short*)(ws + O_BT);
  unsigned short* ybf    = (unsigned short*)(ws + O_YBF);
  unsigned short* xp_bf  = (unsigned short*)(ws + O_XPBF);
  unsigned short* WcombT = (unsigned short*)(ws + O_WCT);
  unsigned short* woutT  = (unsigned short*)(ws + O_WOUTT);
  unsigned short* w_inT  = (unsigned short*)(ws + O_WINT);
  unsigned short* we_bf  = (unsigned short*)(ws + O_WIPE);
  unsigned short* st     = (unsigned short*)(ws + O_ST);
  unsigned short* y2b    = (unsigned short*)(ws + O_Y2);

  prep_misc<<<5676, 256, 0, stream>>>(x, xp_bf, w_in, w_inT, wout, woutT,
                                      w_inp, b_inp, we_bf, Wdt, bdt, wcls, wclsT);
  gemm_bf16<<<dim3(2, 11), 256, 0, stream>>>(w_inT, we_bf, nullptr, WcombT, nullptr, 1408, 224, 256);
  gemm_bf16<<<dim3(10, 128), 256, 0, stream>>>(xp_bf, WcombT, nullptr, zxb, nullptr, 16384, ZXW, 224);
  conv_silu5<<<1536, 256, 0, stream>>>(zxb, convw, convb, Xbf, Bbf, Cbf);
  dt_logits<<<512, 256, 0, stream>>>(x, Wdt, bdt, dtb, dtsp);
  dt_cumsum4<<<128, 256, 0, stream>>>(dtsp, alog, acs);
  trans_g<<<384, 256, 0, stream>>>(Bbf, BbfT, Cbf, Gbf);
  yd_states7<<<1024, 256, 0, stream>>>(Xbf, dtsp, acs, Gbf, BbfT, ybf, st);
  scan_states<<<1024, 256, 0, stream>>>(st, acs);
  yo_combine6<<<512, 256, 0, stream>>>(Xbf, Cbf, st, acs, Dp, ybf);
  gated_rms4<<<4096, 256, 0, stream>>>(ybf, zxb, rmsw);
  gemm_bf16<<<dim3(2, 128), 256, 0, stream>>>(ybf, woutT, nullptr, y2b, nullptr, 16384, DM, DIN);
  ln_cls2<<<4096, 256, 0, stream>>>(y2b, lng, lnb, wclsT, bcls, out);
}